// Round 1
// baseline (204.147 us; speedup 1.0000x reference)
//
#include <hip/hip_runtime.h>

// TenHotEncodeLayer: out[n, x[n,j]] = 1.0, rest zeros.
// B=8192 rows, NUM_TOKENS=32000 cols (f32), K=10 indices/row.
// Memory-bound: 1.048 GB of output writes dominates everything.

#define NUM_TOKENS 32000
#define KHOT 10
#define F4_PER_ROW (NUM_TOKENS / 4)   // 8000 float4 per row (128,000 B, 16B-aligned)
#define BLOCK 256

__global__ __launch_bounds__(BLOCK) void TenHotEncodeLayer_53566832115799_kernel(
    const int* __restrict__ x, float* __restrict__ out) {
    const int row = blockIdx.x;
    // Zero-fill this row with coalesced float4 stores.
    float4* __restrict__ rowp = reinterpret_cast<float4*>(out) + (size_t)row * F4_PER_ROW;
    const float4 z = make_float4(0.f, 0.f, 0.f, 0.f);
    for (int i = threadIdx.x; i < F4_PER_ROW; i += BLOCK) {
        rowp[i] = z;
    }
    // Intra-block barrier: all zero-stores for this row are ordered before the
    // scatter writes below (same block owns the whole row, so no cross-block race).
    __syncthreads();
    if (threadIdx.x < KHOT) {
        const int idx = x[row * KHOT + threadIdx.x];
        if (idx >= 0 && idx < NUM_TOKENS) {
            out[(size_t)row * NUM_TOKENS + idx] = 1.0f;  // set (not add): dup indices OK
        }
    }
}

extern "C" void kernel_launch(void* const* d_in, const int* in_sizes, int n_in,
                              void* d_out, int out_size, void* d_ws, size_t ws_size,
                              hipStream_t stream) {
    const int* x = (const int*)d_in[0];
    float* out = (float*)d_out;
    const int B = in_sizes[0] / KHOT;  // 8192
    TenHotEncodeLayer_53566832115799_kernel<<<B, BLOCK, 0, stream>>>(x, out);
}

// Round 2
// 199.190 us; speedup vs baseline: 1.0249x; 1.0249x over previous
//
#include <hip/hip_runtime.h>

// TenHotEncodeLayer: out[n, x[n,j]] = 1.0, rest zeros.
// B=8192 rows, NUM_TOKENS=32000 cols (f32), K=10 indices/row.
// Single-pass streaming: ones are fused into the zero-fill stream (no
// __syncthreads barrier, no scattered 4B writes). Pure coalesced float4
// stores -> should match fillBufferAligned's measured 6.87 TB/s.

#define NUM_TOKENS 32000
#define KHOT 10
#define F4_PER_ROW (NUM_TOKENS / 4)   // 8000 float4 per row (128,000 B, 16B-aligned)
#define BLOCK 256

__global__ __launch_bounds__(BLOCK) void TenHotEncodeLayer_53566832115799_kernel(
    const int* __restrict__ x, float* __restrict__ out) {
    const int row = blockIdx.x;

    // Preload this row's 10 indices. Address is wave-uniform (row is uniform,
    // j is unrolled) -> compiler emits scalar loads, broadcast to all lanes.
    int   c[KHOT];       // owning float4-chunk of index j (-1 if dropped)
    unsigned bit[KHOT];  // element bit within the chunk (1<<(idx&3))
    #pragma unroll
    for (int j = 0; j < KHOT; ++j) {
        const int idx = x[row * KHOT + j];
        const bool ok = (idx >= 0) && (idx < NUM_TOKENS);
        c[j]   = ok ? (idx >> 2) : -1;   // -1 never matches a chunk id
        bit[j] = 1u << (idx & 3);
    }

    float4* __restrict__ rowp = reinterpret_cast<float4*>(out) + (size_t)row * F4_PER_ROW;
    for (int i = threadIdx.x; i < F4_PER_ROW; i += BLOCK) {
        // 4-bit mask of which elements of this chunk are hot. Duplicate
        // indices OR the same bit (set semantics, not add).
        unsigned m = 0u;
        #pragma unroll
        for (int j = 0; j < KHOT; ++j) {
            m |= (c[j] == i) ? bit[j] : 0u;
        }
        float4 v;
        v.x = (m & 1u) ? 1.0f : 0.0f;
        v.y = (m & 2u) ? 1.0f : 0.0f;
        v.z = (m & 4u) ? 1.0f : 0.0f;
        v.w = (m & 8u) ? 1.0f : 0.0f;
        rowp[i] = v;   // coalesced 16 B/lane streaming store
    }
}

extern "C" void kernel_launch(void* const* d_in, const int* in_sizes, int n_in,
                              void* d_out, int out_size, void* d_ws, size_t ws_size,
                              hipStream_t stream) {
    const int* x = (const int*)d_in[0];
    float* out = (float*)d_out;
    const int B = in_sizes[0] / KHOT;  // 8192
    TenHotEncodeLayer_53566832115799_kernel<<<B, BLOCK, 0, stream>>>(x, out);
}